// Round 2
// baseline (149.423 us; speedup 1.0000x reference)
//
#include <hip/hip_runtime.h>
#include <hip/hip_bf16.h>

// HybridBCEDiceBoundaryLoss — scalar loss over logits/targets (32,1,512,512) fp32.
// loss = 0.3*BCE + 0.3*Dice + 0.2*BoundaryBCE + 0.2*LovaszHinge(per-image mean)
//
// Lovasz without sorting: counts-only histogram over e in (0,8), 1024 bins,
// suffix-scan ranks, bin-midpoint values (2nd-order accurate).
//
// R10: single-compute-kernel. R9 showed the timed region = 2 fixed 256-MiB
// harness poison fills (~84 us) + ~24 us of ours. Changes:
//  - kernelBC fused into kernelA: per-image last-block ticket (threadfence +
//    device-scope atomicAdd, same pattern R9 validated) does the per-image
//    Lovasz/dice; globally-last block folds the scalar. Removes one dispatch+gap.
//  - tickets (33 words) zero-initialized by a 132-B memset node (replaces the
//    4-6 us kernelBC node).
//  - occupancy: 4 rows/wave -> 1024 blocks = 4 blocks/CU = 4 waves/SIMD
//    (was 2), halving latency exposure. Halo re-reads are L3-absorbed.
// kernelA inner loop unchanged (branchless rolling-window, zero in-loop barriers).

#define NB      32
#define HH      512
#define WW      512
#define HW      (HH*WW)          // 262144
#define NTOT    (NB*HW)          // 8388608
#define K_BINS  1024
#define INV_H   128.0f           // K_BINS / 8.0 range
#define BIN_W   (1.0f/128.0f)
#define ROWS    4                // rows per wave
#define BPI     32               // blocks per image (512 rows / (ROWS * 4 waves))

struct Ws {
    unsigned tick[NB];           // per-image completion tickets   (memset to 0)
    unsigned gticket;            // global completion ticket       (memset to 0)
    unsigned cnt[NB*BPI*K_BINS]; // per-block packed hist: low16=all, high16=pos
    float    partf[NB*BPI*5];    // per-block {bce, bceE, sy, spy, P}
    float4   vals[NB];           // per-image {bce, bceE, dice_ratio, lov}
};

__device__ __forceinline__ void process_elem(float x, float y, float wsum,
                                             float& bce_s, float& bceE_s, float& sy_s,
                                             float& spy_s, float& P_s,
                                             unsigned* s_cnt) {
    const float ax = fabsf(x);
    const float t  = __expf(-ax);                       // exp(-|x|)
    const float bce = fmaxf(x, 0.f) - x * y + __logf(1.f + t);
    const float inv = __builtin_amdgcn_rcpf(1.f + t);
    const float s = (x >= 0.f) ? inv : t * inv;         // sigmoid(x)
    const bool edge = (wsum > 0.5f) && (wsum < 8.5f);   // 1..8 of 9 ones

    bce_s  += bce;
    bceE_s += edge ? bce : 0.f;
    sy_s   += s * y;
    spy_s  += s + y;
    P_s    += y;

    const float e = 1.f - x * (2.f * y - 1.f);
    if (e > 0.f) {
        int b = (int)(e * INV_H);
        if (b > K_BINS - 1) b = K_BINS - 1;
        atomicAdd(&s_cnt[b], (y > 0.5f) ? 0x10001u : 1u);
    }
}

__global__ __launch_bounds__(256, 4) void kernelA(const float* __restrict__ logits,
                                                  const float* __restrict__ targets,
                                                  Ws* __restrict__ ws,
                                                  float* __restrict__ out) {
    __shared__ unsigned s_cnt[K_BINS];
    __shared__ float    red[4][5];
    __shared__ double   dred[4];
    __shared__ float    s_P, s_bce, s_bceE, s_dice;
    __shared__ int      s_last, s_fin;

    const int tid  = threadIdx.x;
    const int lane = tid & 63;
    const int wave = tid >> 6;
    for (int i = tid; i < K_BINS; i += 256) s_cnt[i] = 0u;
    __syncthreads();

    const int img   = blockIdx.x >> 5;                   // 32 blocks per image
    const int strip = ((blockIdx.x & 31) << 2) | wave;   // 0..127
    const int r0    = strip * ROWS;                      // this wave: rows r0..r0+3

    const float4* __restrict__ tg4 = (const float4*)(targets + img * HW);
    const float4* __restrict__ lg4 = (const float4*)(logits  + img * HW);
    const int cA = lane;         // f4 cols 4*lane   .. 4*lane+3
    const int cB = 64 + lane;    // f4 cols 256+4*lane ..

    // circular windows: T rows r-1..r+1 live in slots (j)%5,(j+1)%5,(j+2)%5
    float4 T[5][2]; float fT[5];
    float4 X[3][2];

#pragma unroll
    for (int s = 0; s < 5; ++s) {                        // rows r0-1 .. r0+3
        const int rr = r0 - 1 + s;
        const int rc = rr < 0 ? 0 : (rr > 511 ? 511 : rr);
        fT[s] = (rr >= 0 && rr < 512) ? 1.f : 0.f;
        T[s][0] = tg4[rc * 128 + cA];
        T[s][1] = tg4[rc * 128 + cB];
    }
#pragma unroll
    for (int s = 0; s < 3; ++s) {                        // logit rows r0 .. r0+2
        const int rr = r0 + s;
        X[s][0] = lg4[rr * 128 + cA];
        X[s][1] = lg4[rr * 128 + cB];
    }

    float bce_s = 0.f, bceE_s = 0.f, sy_s = 0.f, spy_s = 0.f, P_s = 0.f;

#pragma unroll
    for (int j = 0; j < ROWS; ++j) {
        const int ia = j % 5, ib = (j + 1) % 5, ic = (j + 2) % 5;
        const int xs = j % 3;
        const float fa = fT[ia], fc = fT[ic];

        // column triple-sums for cols 4*lane.. (chunk A) and 256+4*lane.. (chunk B)
        float4 csA, csB;
        csA.x = fmaf(T[ia][0].x, fa, fmaf(T[ic][0].x, fc, T[ib][0].x));
        csA.y = fmaf(T[ia][0].y, fa, fmaf(T[ic][0].y, fc, T[ib][0].y));
        csA.z = fmaf(T[ia][0].z, fa, fmaf(T[ic][0].z, fc, T[ib][0].z));
        csA.w = fmaf(T[ia][0].w, fa, fmaf(T[ic][0].w, fc, T[ib][0].w));
        csB.x = fmaf(T[ia][1].x, fa, fmaf(T[ic][1].x, fc, T[ib][1].x));
        csB.y = fmaf(T[ia][1].y, fa, fmaf(T[ic][1].y, fc, T[ib][1].y));
        csB.z = fmaf(T[ia][1].z, fa, fmaf(T[ic][1].z, fc, T[ib][1].z));
        csB.w = fmaf(T[ia][1].w, fa, fmaf(T[ic][1].w, fc, T[ib][1].w));

        // neighbor columns via shuffles (wave owns the full 512-col row)
        const float upA  = __shfl_up(csA.w, 1);
        const float dnA  = __shfl_down(csA.x, 1);
        const float upB  = __shfl_up(csB.w, 1);
        const float dnB  = __shfl_down(csB.x, 1);
        const float bc0  = __shfl(csB.x, 0);    // col 256 triple-sum
        const float bc63 = __shfl(csA.w, 63);   // col 255 triple-sum
        const float LA = (lane == 0)  ? 0.f  : upA;
        const float RA = (lane == 63) ? bc0  : dnA;
        const float LB = (lane == 0)  ? bc63 : upB;
        const float RB = (lane == 63) ? 0.f  : dnB;

        process_elem(X[xs][0].x, T[ib][0].x, LA + csA.x + csA.y,    bce_s, bceE_s, sy_s, spy_s, P_s, s_cnt);
        process_elem(X[xs][0].y, T[ib][0].y, csA.x + csA.y + csA.z, bce_s, bceE_s, sy_s, spy_s, P_s, s_cnt);
        process_elem(X[xs][0].z, T[ib][0].z, csA.y + csA.z + csA.w, bce_s, bceE_s, sy_s, spy_s, P_s, s_cnt);
        process_elem(X[xs][0].w, T[ib][0].w, csA.z + csA.w + RA,    bce_s, bceE_s, sy_s, spy_s, P_s, s_cnt);
        process_elem(X[xs][1].x, T[ib][1].x, LB + csB.x + csB.y,    bce_s, bceE_s, sy_s, spy_s, P_s, s_cnt);
        process_elem(X[xs][1].y, T[ib][1].y, csB.x + csB.y + csB.z, bce_s, bceE_s, sy_s, spy_s, P_s, s_cnt);
        process_elem(X[xs][1].z, T[ib][1].z, csB.y + csB.z + csB.w, bce_s, bceE_s, sy_s, spy_s, P_s, s_cnt);
        process_elem(X[xs][1].w, T[ib][1].w, csB.z + csB.w + RB,    bce_s, bceE_s, sy_s, spy_s, P_s, s_cnt);

        // prefetch (compile-time pruned; distance = 3 steps)
        if (j < ROWS - 3) {
            const int rr = r0 + j + 4;                   // target row, may be 512 at last strip
            const int rc = rr > 511 ? 511 : rr;
            fT[ia] = (rr < 512) ? 1.f : 0.f;
            T[ia][0] = tg4[rc * 128 + cA];
            T[ia][1] = tg4[rc * 128 + cB];
            const int rx = r0 + j + 3;                   // logit row, always <= 511
            X[xs][0] = lg4[rx * 128 + cA];
            X[xs][1] = lg4[rx * 128 + cB];
        }
    }
    __syncthreads();

    // flush per-block histogram to its own global slice: plain coalesced stores.
    unsigned* g_c = ws->cnt + blockIdx.x * K_BINS;
    for (int i = tid; i < K_BINS; i += 256) g_c[i] = s_cnt[i];

    // block reduction of 5 accumulators
    for (int off = 32; off; off >>= 1) {
        bce_s  += __shfl_down(bce_s, off);
        bceE_s += __shfl_down(bceE_s, off);
        sy_s   += __shfl_down(sy_s, off);
        spy_s  += __shfl_down(spy_s, off);
        P_s    += __shfl_down(P_s, off);
    }
    if (lane == 0) {
        red[wave][0] = bce_s; red[wave][1] = bceE_s; red[wave][2] = sy_s;
        red[wave][3] = spy_s; red[wave][4] = P_s;
    }
    __syncthreads();   // also drains all waves' global stores (vmcnt(0) before barrier)
    if (tid == 0) {
        float a = 0.f, b = 0.f, c2 = 0.f, d = 0.f, e2 = 0.f;
        for (int w = 0; w < 4; ++w) {
            a += red[w][0]; b += red[w][1]; c2 += red[w][2];
            d += red[w][3]; e2 += red[w][4];
        }
        float* pf = ws->partf + blockIdx.x * 5;
        pf[0] = a; pf[1] = b; pf[2] = c2; pf[3] = d; pf[4] = e2;
        __threadfence();                                  // release hist + partials
        const unsigned old = atomicAdd(&ws->tick[img], 1u);
        s_last = (old == BPI - 1) ? 1 : 0;
    }
    __syncthreads();
    if (!s_last) return;

    // ================= per-image reduction (last block of this image) =========
    __threadfence();                                      // acquire other blocks' data

    // ---- reduce the 32 per-block float partials of this image (wave 0) ----
    float pf0 = 0.f, pf1 = 0.f, pf2 = 0.f, pf3 = 0.f, pf4 = 0.f;
    if (tid < BPI) {
        const float* p = ws->partf + (img * BPI + tid) * 5;
        pf0 = p[0]; pf1 = p[1]; pf2 = p[2]; pf3 = p[3]; pf4 = p[4];
    }
    if (tid < 64) {
        for (int off = 16; off; off >>= 1) {
            pf0 += __shfl_down(pf0, off);
            pf1 += __shfl_down(pf1, off);
            pf2 += __shfl_down(pf2, off);
            pf3 += __shfl_down(pf3, off);
            pf4 += __shfl_down(pf4, off);
        }
        if (tid == 0) {
            s_bce  = pf0;
            s_bceE = pf1;
            s_dice = 2.f * pf2 / (pf3 + 1e-7f);
            s_P    = pf4;
        }
    }

    // ---- gather 4 bins/thread (descending-bin order), summing 32 sub-hists ----
    const unsigned* __restrict__ cn = ws->cnt + img * BPI * K_BINS;
    unsigned la[4], lp[4];
    float    me[4];
    unsigned tot_a = 0, tot_p = 0;
#pragma unroll
    for (int j = 0; j < 4; ++j) {
        const int k = K_BINS - 1 - (tid * 4 + j);
        unsigned a = 0, p = 0;
#pragma unroll
        for (int b = 0; b < BPI; ++b) {
            const unsigned cpk = cn[b * K_BINS + k];
            a += cpk & 0xFFFFu;                          // per-slice unpack: 32-bit safe
            p += cpk >> 16;
        }
        la[j] = a; lp[j] = p;
        me[j] = ((float)k + 0.5f) * BIN_W;               // bin-midpoint error value
        tot_a += a; tot_p += p;
    }

    // block-wide inclusive scan of per-thread totals (reuse s_cnt LDS)
    unsigned* sc_a = s_cnt;
    unsigned* sc_p = s_cnt + 256;
    sc_a[tid] = tot_a; sc_p[tid] = tot_p;
    __syncthreads();
    for (int off = 1; off < 256; off <<= 1) {
        unsigned va = (tid >= off) ? sc_a[tid - off] : 0u;
        unsigned vp = (tid >= off) ? sc_p[tid - off] : 0u;
        __syncthreads();
        sc_a[tid] += va; sc_p[tid] += vp;
        __syncthreads();
    }
    const unsigned excl_a = sc_a[tid] - tot_a;
    const unsigned excl_p = sc_p[tid] - tot_p;

    const double P = (double)s_P;
    double run_a = (double)excl_a, run_p = (double)excl_p;
    double contrib = 0.0;
#pragma unroll
    for (int j = 0; j < 4; ++j) {
        const double m = (double)la[j];
        const double p = (double)lp[j];
        if (la[j]) {
            const double u = P + (run_a + 0.5 * m) - (run_p + 0.5 * p);
            const double c = run_p + 0.5 * p;
            contrib += (double)(lp[j] * me[j]) / u;                  // positives: dJ = 1/u
            const double den = u * (u - 1.0);
            if (den > 0.0)
                contrib += (double)((la[j] - lp[j]) * me[j]) * (P - c) / den;  // negatives
        }
        run_a += m; run_p += p;
    }

    for (int off = 32; off; off >>= 1) contrib += __shfl_down(contrib, off);
    if (lane == 0) dred[wave] = contrib;
    __syncthreads();

    if (tid == 0) {
        const double tot = dred[0] + dred[1] + dred[2] + dred[3];
        float4 v;
        v.x = s_bce; v.y = s_bceE; v.z = s_dice; v.w = (float)tot;
        ws->vals[img] = v;
        __threadfence();                                 // release per-image result
        const unsigned gold = atomicAdd(&ws->gticket, 1u);
        s_fin = (gold == NB - 1) ? 1 : 0;
    }
    __syncthreads();
    if (!s_fin) return;

    // ================= final fold (globally-last block) =======================
    __threadfence();                                     // acquire other images' vals
    if (tid < 64) {
        float vx = 0.f, vy = 0.f, vz = 0.f, vw = 0.f;
        if (tid < NB) {
            const float4 v = ws->vals[tid];
            vx = v.x; vy = v.y; vz = v.z; vw = v.w;
        }
        for (int off = 16; off; off >>= 1) {
            vx += __shfl_down(vx, off);
            vy += __shfl_down(vy, off);
            vz += __shfl_down(vz, off);
            vw += __shfl_down(vw, off);
        }
        if (tid == 0) {
            const float invN = 1.f / (float)NTOT;
            const float bce      = vx * invN;
            const float boundary = (vx + 2.f * vy) * invN;
            const float dice     = 1.f - vz / (float)NB;
            const float lov      = vw / (float)NB;
            out[0] = 0.3f * bce + 0.3f * dice + 0.2f * boundary + 0.2f * lov;
        }
    }
}

extern "C" void kernel_launch(void* const* d_in, const int* in_sizes, int n_in,
                              void* d_out, int out_size, void* d_ws, size_t ws_size,
                              hipStream_t stream) {
    const float* logits  = (const float*)d_in[0];
    const float* targets = (const float*)d_in[1];
    float* out = (float*)d_out;
    Ws* ws = (Ws*)d_ws;

    // zero only the 33 ticket words (tick[32] + gticket, at the front of Ws)
    (void)hipMemsetAsync(d_ws, 0, (NB + 1) * sizeof(unsigned), stream);
    kernelA<<<NB * BPI, 256, 0, stream>>>(logits, targets, ws, out);
}

// Round 3
// 113.444 us; speedup vs baseline: 1.3171x; 1.3171x over previous
//
#include <hip/hip_runtime.h>
#include <hip/hip_bf16.h>

// HybridBCEDiceBoundaryLoss — scalar loss over logits/targets (32,1,512,512) fp32.
// loss = 0.3*BCE + 0.3*Dice + 0.2*BoundaryBCE + 0.2*LovaszHinge(per-image mean)
//
// Lovasz without sorting: counts-only histogram over e in (0,8), 1024 bins,
// suffix-scan ranks, bin-midpoint values (2nd-order accurate).
//
// R11: single-kernel WITHOUT device fences. R10's regression (kernelA 15->79us,
// VALUBusy 13%) was the 1024 per-block __threadfence() calls: agent-scope
// release on multi-XCD gfx9 = buffer_wbl2 (FULL L2 writeback) and the acquire
// side = buffer_inv (full L2 invalidate, nuking inputs cached for in-flight
// blocks). Replacement protocol, no fences anywhere:
//   - publish cross-block data with agent-scope RELAXED atomic stores
//     (sc1 write-through: line-granular, straight to the coherence point)
//   - explicit per-wave `s_waitcnt vmcnt(0)` before the ticket RMW = release
//     (stores are already coherent once retired; no wbl2 needed)
//   - consumers use agent-scope relaxed atomic loads (bypass stale local L2;
//     no buffer_inv)
// Also reverts R10's ROWS=4 confound: back to R8/R9 known-good geometry
// (8 rows/wave, 512 blocks, 2 blocks/CU).

#define NB      32
#define HH      512
#define WW      512
#define HW      (HH*WW)          // 262144
#define NTOT    (NB*HW)          // 8388608
#define K_BINS  1024
#define INV_H   128.0f           // K_BINS / 8.0 range
#define BIN_W   (1.0f/128.0f)
#define BPI     16               // blocks per image

#define AGENT   __HIP_MEMORY_SCOPE_AGENT

struct Ws {
    unsigned tick[NB];           // per-image completion tickets   (memset to 0)
    unsigned gticket;            // global completion ticket       (memset to 0)
    unsigned cnt[NB*BPI*K_BINS]; // per-block packed hist: low16=all, high16=pos
    float    partf[NB*BPI*5];    // per-block {bce, bceE, sy, spy, P}
    float    vals[NB*4];         // per-image {bce, bceE, dice_ratio, lov}
};

__device__ __forceinline__ void process_elem(float x, float y, float wsum,
                                             float& bce_s, float& bceE_s, float& sy_s,
                                             float& spy_s, float& P_s,
                                             unsigned* s_cnt) {
    const float ax = fabsf(x);
    const float t  = __expf(-ax);                       // exp(-|x|)
    const float bce = fmaxf(x, 0.f) - x * y + __logf(1.f + t);
    const float inv = __builtin_amdgcn_rcpf(1.f + t);
    const float s = (x >= 0.f) ? inv : t * inv;         // sigmoid(x)
    const bool edge = (wsum > 0.5f) && (wsum < 8.5f);   // 1..8 of 9 ones

    bce_s  += bce;
    bceE_s += edge ? bce : 0.f;
    sy_s   += s * y;
    spy_s  += s + y;
    P_s    += y;

    const float e = 1.f - x * (2.f * y - 1.f);
    if (e > 0.f) {
        int b = (int)(e * INV_H);
        if (b > K_BINS - 1) b = K_BINS - 1;
        atomicAdd(&s_cnt[b], (y > 0.5f) ? 0x10001u : 1u);
    }
}

__global__ __launch_bounds__(256, 2) void kernelA(const float* __restrict__ logits,
                                                  const float* __restrict__ targets,
                                                  Ws* __restrict__ ws,
                                                  float* __restrict__ out) {
    __shared__ unsigned s_cnt[K_BINS];
    __shared__ float    red[4][5];
    __shared__ double   dred[4];
    __shared__ float    s_P, s_bce, s_bceE, s_dice;
    __shared__ int      s_last, s_fin;

    const int tid  = threadIdx.x;
    const int lane = tid & 63;
    const int wave = tid >> 6;
    for (int i = tid; i < K_BINS; i += 256) s_cnt[i] = 0u;
    __syncthreads();

    const int img   = blockIdx.x >> 4;                   // 16 blocks per image
    const int strip = ((blockIdx.x & 15) << 2) | wave;   // 0..63
    const int r0    = strip * 8;                         // this wave: rows r0..r0+7

    const float4* __restrict__ tg4 = (const float4*)(targets + img * HW);
    const float4* __restrict__ lg4 = (const float4*)(logits  + img * HW);
    const int cA = lane;         // f4 cols 4*lane   .. 4*lane+3
    const int cB = 64 + lane;    // f4 cols 256+4*lane ..

    // circular windows: T rows r-1..r+1 live in slots (j)%5,(j+1)%5,(j+2)%5
    float4 T[5][2]; float fT[5];
    float4 X[3][2];

#pragma unroll
    for (int s = 0; s < 5; ++s) {                        // rows r0-1 .. r0+3
        const int rr = r0 - 1 + s;
        const int rc = rr < 0 ? 0 : (rr > 511 ? 511 : rr);
        fT[s] = (rr >= 0 && rr < 512) ? 1.f : 0.f;
        T[s][0] = tg4[rc * 128 + cA];
        T[s][1] = tg4[rc * 128 + cB];
    }
#pragma unroll
    for (int s = 0; s < 3; ++s) {                        // logit rows r0 .. r0+2
        const int rr = r0 + s;
        X[s][0] = lg4[rr * 128 + cA];
        X[s][1] = lg4[rr * 128 + cB];
    }

    float bce_s = 0.f, bceE_s = 0.f, sy_s = 0.f, spy_s = 0.f, P_s = 0.f;

#pragma unroll
    for (int j = 0; j < 8; ++j) {
        const int ia = j % 5, ib = (j + 1) % 5, ic = (j + 2) % 5;
        const int xs = j % 3;
        const float fa = fT[ia], fc = fT[ic];

        // column triple-sums for cols 4*lane.. (chunk A) and 256+4*lane.. (chunk B)
        float4 csA, csB;
        csA.x = fmaf(T[ia][0].x, fa, fmaf(T[ic][0].x, fc, T[ib][0].x));
        csA.y = fmaf(T[ia][0].y, fa, fmaf(T[ic][0].y, fc, T[ib][0].y));
        csA.z = fmaf(T[ia][0].z, fa, fmaf(T[ic][0].z, fc, T[ib][0].z));
        csA.w = fmaf(T[ia][0].w, fa, fmaf(T[ic][0].w, fc, T[ib][0].w));
        csB.x = fmaf(T[ia][1].x, fa, fmaf(T[ic][1].x, fc, T[ib][1].x));
        csB.y = fmaf(T[ia][1].y, fa, fmaf(T[ic][1].y, fc, T[ib][1].y));
        csB.z = fmaf(T[ia][1].z, fa, fmaf(T[ic][1].z, fc, T[ib][1].z));
        csB.w = fmaf(T[ia][1].w, fa, fmaf(T[ic][1].w, fc, T[ib][1].w));

        // neighbor columns via shuffles (wave owns the full 512-col row)
        const float upA  = __shfl_up(csA.w, 1);
        const float dnA  = __shfl_down(csA.x, 1);
        const float upB  = __shfl_up(csB.w, 1);
        const float dnB  = __shfl_down(csB.x, 1);
        const float bc0  = __shfl(csB.x, 0);    // col 256 triple-sum
        const float bc63 = __shfl(csA.w, 63);   // col 255 triple-sum
        const float LA = (lane == 0)  ? 0.f  : upA;
        const float RA = (lane == 63) ? bc0  : dnA;
        const float LB = (lane == 0)  ? bc63 : upB;
        const float RB = (lane == 63) ? 0.f  : dnB;

        process_elem(X[xs][0].x, T[ib][0].x, LA + csA.x + csA.y,    bce_s, bceE_s, sy_s, spy_s, P_s, s_cnt);
        process_elem(X[xs][0].y, T[ib][0].y, csA.x + csA.y + csA.z, bce_s, bceE_s, sy_s, spy_s, P_s, s_cnt);
        process_elem(X[xs][0].z, T[ib][0].z, csA.y + csA.z + csA.w, bce_s, bceE_s, sy_s, spy_s, P_s, s_cnt);
        process_elem(X[xs][0].w, T[ib][0].w, csA.z + csA.w + RA,    bce_s, bceE_s, sy_s, spy_s, P_s, s_cnt);
        process_elem(X[xs][1].x, T[ib][1].x, LB + csB.x + csB.y,    bce_s, bceE_s, sy_s, spy_s, P_s, s_cnt);
        process_elem(X[xs][1].y, T[ib][1].y, csB.x + csB.y + csB.z, bce_s, bceE_s, sy_s, spy_s, P_s, s_cnt);
        process_elem(X[xs][1].z, T[ib][1].z, csB.y + csB.z + csB.w, bce_s, bceE_s, sy_s, spy_s, P_s, s_cnt);
        process_elem(X[xs][1].w, T[ib][1].w, csB.z + csB.w + RB,    bce_s, bceE_s, sy_s, spy_s, P_s, s_cnt);

        // prefetch (compile-time pruned; distance = 3 steps)
        if (j < 5) {
            const int rr = r0 + j + 4;                   // target row, may be 512 at last strip
            const int rc = rr > 511 ? 511 : rr;
            fT[ia] = (rr < 512) ? 1.f : 0.f;
            T[ia][0] = tg4[rc * 128 + cA];
            T[ia][1] = tg4[rc * 128 + cB];
            const int rx = r0 + j + 3;                   // logit row, always <= 511
            X[xs][0] = lg4[rx * 128 + cA];
            X[xs][1] = lg4[rx * 128 + cB];
        }
    }
    __syncthreads();

    // flush per-block histogram to its own global slice with agent-scope
    // RELAXED stores (sc1 write-through; line-granular, no L2 writeback).
    unsigned* g_c = ws->cnt + blockIdx.x * K_BINS;
    for (int i = tid; i < K_BINS; i += 256)
        __hip_atomic_store(&g_c[i], s_cnt[i], __ATOMIC_RELAXED, AGENT);

    // block reduction of 5 accumulators
    for (int off = 32; off; off >>= 1) {
        bce_s  += __shfl_down(bce_s, off);
        bceE_s += __shfl_down(bceE_s, off);
        sy_s   += __shfl_down(sy_s, off);
        spy_s  += __shfl_down(spy_s, off);
        P_s    += __shfl_down(P_s, off);
    }
    if (lane == 0) {
        red[wave][0] = bce_s; red[wave][1] = bceE_s; red[wave][2] = sy_s;
        red[wave][3] = spy_s; red[wave][4] = P_s;
    }
    // release part 1: every wave drains its own sc1 hist stores to the
    // coherence point BEFORE signalling readiness via the barrier.
    asm volatile("s_waitcnt vmcnt(0)" ::: "memory");
    __syncthreads();

    if (tid == 0) {
        float a = 0.f, b = 0.f, c2 = 0.f, d = 0.f, e2 = 0.f;
        for (int w = 0; w < 4; ++w) {
            a += red[w][0]; b += red[w][1]; c2 += red[w][2];
            d += red[w][3]; e2 += red[w][4];
        }
        float* pf = ws->partf + blockIdx.x * 5;
        __hip_atomic_store(&pf[0], a,  __ATOMIC_RELAXED, AGENT);
        __hip_atomic_store(&pf[1], b,  __ATOMIC_RELAXED, AGENT);
        __hip_atomic_store(&pf[2], c2, __ATOMIC_RELAXED, AGENT);
        __hip_atomic_store(&pf[3], d,  __ATOMIC_RELAXED, AGENT);
        __hip_atomic_store(&pf[4], e2, __ATOMIC_RELAXED, AGENT);
        // release part 2: drain partf, then publish the ticket (relaxed RMW —
        // prior sc1 stores are already at the coherence point).
        asm volatile("s_waitcnt vmcnt(0)" ::: "memory");
        const unsigned old = __hip_atomic_fetch_add(&ws->tick[img], 1u,
                                                    __ATOMIC_RELAXED, AGENT);
        s_last = (old == BPI - 1) ? 1 : 0;
    }
    __syncthreads();
    if (!s_last) return;

    // ================= per-image reduction (last block of this image) =========
    // acquire: agent-scope relaxed loads bypass the (possibly stale) local L2.

    // ---- reduce the 16 per-block float partials of this image (wave 0) ----
    float pf0 = 0.f, pf1 = 0.f, pf2 = 0.f, pf3 = 0.f, pf4 = 0.f;
    if (tid < BPI) {
        const float* p = ws->partf + (img * BPI + tid) * 5;
        pf0 = __hip_atomic_load(&p[0], __ATOMIC_RELAXED, AGENT);
        pf1 = __hip_atomic_load(&p[1], __ATOMIC_RELAXED, AGENT);
        pf2 = __hip_atomic_load(&p[2], __ATOMIC_RELAXED, AGENT);
        pf3 = __hip_atomic_load(&p[3], __ATOMIC_RELAXED, AGENT);
        pf4 = __hip_atomic_load(&p[4], __ATOMIC_RELAXED, AGENT);
    }
    if (tid < 64) {
        for (int off = 8; off; off >>= 1) {
            pf0 += __shfl_down(pf0, off);
            pf1 += __shfl_down(pf1, off);
            pf2 += __shfl_down(pf2, off);
            pf3 += __shfl_down(pf3, off);
            pf4 += __shfl_down(pf4, off);
        }
        if (tid == 0) {
            s_bce  = pf0;
            s_bceE = pf1;
            s_dice = 2.f * pf2 / (pf3 + 1e-7f);
            s_P    = pf4;
        }
    }

    // ---- gather 4 bins/thread (descending-bin order), summing 16 sub-hists ----
    const unsigned* __restrict__ cn = ws->cnt + img * BPI * K_BINS;
    unsigned la[4], lp[4];
    float    me[4];
    unsigned tot_a = 0, tot_p = 0;
#pragma unroll
    for (int j = 0; j < 4; ++j) {
        const int k = K_BINS - 1 - (tid * 4 + j);
        unsigned a = 0, p = 0;
#pragma unroll
        for (int b = 0; b < BPI; ++b) {
            const unsigned cpk = __hip_atomic_load(&cn[b * K_BINS + k],
                                                   __ATOMIC_RELAXED, AGENT);
            a += cpk & 0xFFFFu;                          // per-slice unpack: 32-bit safe
            p += cpk >> 16;
        }
        la[j] = a; lp[j] = p;
        me[j] = ((float)k + 0.5f) * BIN_W;               // bin-midpoint error value
        tot_a += a; tot_p += p;
    }

    // block-wide inclusive scan of per-thread totals (reuse s_cnt LDS)
    unsigned* sc_a = s_cnt;
    unsigned* sc_p = s_cnt + 256;
    sc_a[tid] = tot_a; sc_p[tid] = tot_p;
    __syncthreads();
    for (int off = 1; off < 256; off <<= 1) {
        unsigned va = (tid >= off) ? sc_a[tid - off] : 0u;
        unsigned vp = (tid >= off) ? sc_p[tid - off] : 0u;
        __syncthreads();
        sc_a[tid] += va; sc_p[tid] += vp;
        __syncthreads();
    }
    const unsigned excl_a = sc_a[tid] - tot_a;
    const unsigned excl_p = sc_p[tid] - tot_p;

    const double P = (double)s_P;
    double run_a = (double)excl_a, run_p = (double)excl_p;
    double contrib = 0.0;
#pragma unroll
    for (int j = 0; j < 4; ++j) {
        const double m = (double)la[j];
        const double p = (double)lp[j];
        if (la[j]) {
            const double u = P + (run_a + 0.5 * m) - (run_p + 0.5 * p);
            const double c = run_p + 0.5 * p;
            contrib += (double)(lp[j] * me[j]) / u;                  // positives: dJ = 1/u
            const double den = u * (u - 1.0);
            if (den > 0.0)
                contrib += (double)((la[j] - lp[j]) * me[j]) * (P - c) / den;  // negatives
        }
        run_a += m; run_p += p;
    }

    for (int off = 32; off; off >>= 1) contrib += __shfl_down(contrib, off);
    if (lane == 0) dred[wave] = contrib;
    __syncthreads();

    if (tid == 0) {
        const double tot = dred[0] + dred[1] + dred[2] + dred[3];
        float* vv = ws->vals + img * 4;
        __hip_atomic_store(&vv[0], s_bce,       __ATOMIC_RELAXED, AGENT);
        __hip_atomic_store(&vv[1], s_bceE,      __ATOMIC_RELAXED, AGENT);
        __hip_atomic_store(&vv[2], s_dice,      __ATOMIC_RELAXED, AGENT);
        __hip_atomic_store(&vv[3], (float)tot,  __ATOMIC_RELAXED, AGENT);
        asm volatile("s_waitcnt vmcnt(0)" ::: "memory");
        const unsigned gold = __hip_atomic_fetch_add(&ws->gticket, 1u,
                                                     __ATOMIC_RELAXED, AGENT);
        s_fin = (gold == NB - 1) ? 1 : 0;
    }
    __syncthreads();
    if (!s_fin) return;

    // ================= final fold (globally-last block) =======================
    if (tid < 64) {
        float vx = 0.f, vy = 0.f, vz = 0.f, vw = 0.f;
        if (tid < NB) {
            const float* vv = ws->vals + tid * 4;
            vx = __hip_atomic_load(&vv[0], __ATOMIC_RELAXED, AGENT);
            vy = __hip_atomic_load(&vv[1], __ATOMIC_RELAXED, AGENT);
            vz = __hip_atomic_load(&vv[2], __ATOMIC_RELAXED, AGENT);
            vw = __hip_atomic_load(&vv[3], __ATOMIC_RELAXED, AGENT);
        }
        for (int off = 16; off; off >>= 1) {
            vx += __shfl_down(vx, off);
            vy += __shfl_down(vy, off);
            vz += __shfl_down(vz, off);
            vw += __shfl_down(vw, off);
        }
        if (tid == 0) {
            const float invN = 1.f / (float)NTOT;
            const float bce      = vx * invN;
            const float boundary = (vx + 2.f * vy) * invN;
            const float dice     = 1.f - vz / (float)NB;
            const float lov      = vw / (float)NB;
            out[0] = 0.3f * bce + 0.3f * dice + 0.2f * boundary + 0.2f * lov;
        }
    }
}

extern "C" void kernel_launch(void* const* d_in, const int* in_sizes, int n_in,
                              void* d_out, int out_size, void* d_ws, size_t ws_size,
                              hipStream_t stream) {
    const float* logits  = (const float*)d_in[0];
    const float* targets = (const float*)d_in[1];
    float* out = (float*)d_out;
    Ws* ws = (Ws*)d_ws;

    // zero only the 33 ticket words (tick[32] + gticket, at the front of Ws)
    (void)hipMemsetAsync(d_ws, 0, (NB + 1) * sizeof(unsigned), stream);
    kernelA<<<NB * BPI, 256, 0, stream>>>(logits, targets, ws, out);
}

// Round 4
// 107.538 us; speedup vs baseline: 1.3895x; 1.0549x over previous
//
#include <hip/hip_runtime.h>
#include <hip/hip_bf16.h>

// HybridBCEDiceBoundaryLoss — scalar loss over logits/targets (32,1,512,512) fp32.
// loss = 0.3*BCE + 0.3*Dice + 0.2*BoundaryBCE + 0.2*LovaszHinge(per-image mean)
//
// Lovasz without sorting: counts-only histogram over e in (0,8), 1024 bins,
// suffix-scan ranks, bin-midpoint values (2nd-order accurate).
//
// R12: R9's proven two-kernel structure (108 us known-good) + the ISOLATED
// occupancy lever R10 confounded with fences:
//  - kernelA: 4 rows/wave -> 1024 blocks = 4 blocks/CU = 4 waves/SIMD
//    (R9 was grid-limited to 2). R10's counters showed kernelA VALU-busy
//    ~10.5us and HBM floor ~7-9us (L3 retains inputs); R9's ~15us kernelA is
//    ~4-5us of overlap slack -> more waves/SIMD to hide it.
//  - kernelBC: gathers 32 sub-hists/image; final fold uses the R11-validated
//    sc1 protocol (agent-scope relaxed stores + vmcnt drain + relaxed RMW)
//    instead of __threadfence (no wbl2/inv).
//  - 2 graph nodes, no memset (ticket zeroed by kernelA block 0; hist/partf
//    are plain stores made visible by the kernel boundary).

#define NB      32
#define HH      512
#define WW      512
#define HW      (HH*WW)          // 262144
#define NTOT    (NB*HW)          // 8388608
#define K_BINS  1024
#define INV_H   128.0f           // K_BINS / 8.0 range
#define BIN_W   (1.0f/128.0f)
#define ROWS    4                // rows per wave
#define BPI     32               // kernelA blocks per image

#define AGENT   __HIP_MEMORY_SCOPE_AGENT

struct Ws {
    unsigned ticket;             // zeroed by kernelA block 0 (stream-ordered)
    unsigned cnt[NB*BPI*K_BINS]; // per-block packed hist: low16=all, high16=pos (4 MB)
    float    partf[NB*BPI*5];    // per-block {bce, bceE, sy, spy, P}
    float    vals[NB*4];         // per-image {bce, bceE, dice_ratio, lov}
};

__device__ __forceinline__ void process_elem(float x, float y, float wsum,
                                             float& bce_s, float& bceE_s, float& sy_s,
                                             float& spy_s, float& P_s,
                                             unsigned* s_cnt) {
    const float ax = fabsf(x);
    const float t  = __expf(-ax);                       // exp(-|x|)
    const float bce = fmaxf(x, 0.f) - x * y + __logf(1.f + t);
    const float inv = __builtin_amdgcn_rcpf(1.f + t);
    const float s = (x >= 0.f) ? inv : t * inv;         // sigmoid(x)
    const bool edge = (wsum > 0.5f) && (wsum < 8.5f);   // 1..8 of 9 ones

    bce_s  += bce;
    bceE_s += edge ? bce : 0.f;
    sy_s   += s * y;
    spy_s  += s + y;
    P_s    += y;

    const float e = 1.f - x * (2.f * y - 1.f);
    if (e > 0.f) {
        int b = (int)(e * INV_H);
        if (b > K_BINS - 1) b = K_BINS - 1;
        atomicAdd(&s_cnt[b], (y > 0.5f) ? 0x10001u : 1u);
    }
}

__global__ __launch_bounds__(256, 4) void kernelA(const float* __restrict__ logits,
                                                  const float* __restrict__ targets,
                                                  Ws* __restrict__ ws) {
    __shared__ unsigned s_cnt[K_BINS];
    __shared__ float    red[4][5];

    const int tid  = threadIdx.x;
    const int lane = tid & 63;
    const int wave = tid >> 6;
    for (int i = tid; i < K_BINS; i += 256) s_cnt[i] = 0u;
    __syncthreads();

    const int img   = blockIdx.x >> 5;                   // 32 blocks per image
    const int strip = ((blockIdx.x & 31) << 2) | wave;   // 0..127
    const int r0    = strip * ROWS;                      // this wave: rows r0..r0+3

    const float4* __restrict__ tg4 = (const float4*)(targets + img * HW);
    const float4* __restrict__ lg4 = (const float4*)(logits  + img * HW);
    const int cA = lane;         // f4 cols 4*lane   .. 4*lane+3
    const int cB = 64 + lane;    // f4 cols 256+4*lane ..

    // circular windows: T rows r-1..r+1 live in slots (j)%5,(j+1)%5,(j+2)%5
    float4 T[5][2]; float fT[5];
    float4 X[3][2];

#pragma unroll
    for (int s = 0; s < 5; ++s) {                        // rows r0-1 .. r0+3
        const int rr = r0 - 1 + s;
        const int rc = rr < 0 ? 0 : (rr > 511 ? 511 : rr);
        fT[s] = (rr >= 0 && rr < 512) ? 1.f : 0.f;
        T[s][0] = tg4[rc * 128 + cA];
        T[s][1] = tg4[rc * 128 + cB];
    }
#pragma unroll
    for (int s = 0; s < 3; ++s) {                        // logit rows r0 .. r0+2
        const int rr = r0 + s;
        X[s][0] = lg4[rr * 128 + cA];
        X[s][1] = lg4[rr * 128 + cB];
    }

    float bce_s = 0.f, bceE_s = 0.f, sy_s = 0.f, spy_s = 0.f, P_s = 0.f;

#pragma unroll
    for (int j = 0; j < ROWS; ++j) {
        const int ia = j % 5, ib = (j + 1) % 5, ic = (j + 2) % 5;
        const int xs = j % 3;
        const float fa = fT[ia], fc = fT[ic];

        // column triple-sums for cols 4*lane.. (chunk A) and 256+4*lane.. (chunk B)
        float4 csA, csB;
        csA.x = fmaf(T[ia][0].x, fa, fmaf(T[ic][0].x, fc, T[ib][0].x));
        csA.y = fmaf(T[ia][0].y, fa, fmaf(T[ic][0].y, fc, T[ib][0].y));
        csA.z = fmaf(T[ia][0].z, fa, fmaf(T[ic][0].z, fc, T[ib][0].z));
        csA.w = fmaf(T[ia][0].w, fa, fmaf(T[ic][0].w, fc, T[ib][0].w));
        csB.x = fmaf(T[ia][1].x, fa, fmaf(T[ic][1].x, fc, T[ib][1].x));
        csB.y = fmaf(T[ia][1].y, fa, fmaf(T[ic][1].y, fc, T[ib][1].y));
        csB.z = fmaf(T[ia][1].z, fa, fmaf(T[ic][1].z, fc, T[ib][1].z));
        csB.w = fmaf(T[ia][1].w, fa, fmaf(T[ic][1].w, fc, T[ib][1].w));

        // neighbor columns via shuffles (wave owns the full 512-col row)
        const float upA  = __shfl_up(csA.w, 1);
        const float dnA  = __shfl_down(csA.x, 1);
        const float upB  = __shfl_up(csB.w, 1);
        const float dnB  = __shfl_down(csB.x, 1);
        const float bc0  = __shfl(csB.x, 0);    // col 256 triple-sum
        const float bc63 = __shfl(csA.w, 63);   // col 255 triple-sum
        const float LA = (lane == 0)  ? 0.f  : upA;
        const float RA = (lane == 63) ? bc0  : dnA;
        const float LB = (lane == 0)  ? bc63 : upB;
        const float RB = (lane == 63) ? 0.f  : dnB;

        process_elem(X[xs][0].x, T[ib][0].x, LA + csA.x + csA.y,    bce_s, bceE_s, sy_s, spy_s, P_s, s_cnt);
        process_elem(X[xs][0].y, T[ib][0].y, csA.x + csA.y + csA.z, bce_s, bceE_s, sy_s, spy_s, P_s, s_cnt);
        process_elem(X[xs][0].z, T[ib][0].z, csA.y + csA.z + csA.w, bce_s, bceE_s, sy_s, spy_s, P_s, s_cnt);
        process_elem(X[xs][0].w, T[ib][0].w, csA.z + csA.w + RA,    bce_s, bceE_s, sy_s, spy_s, P_s, s_cnt);
        process_elem(X[xs][1].x, T[ib][1].x, LB + csB.x + csB.y,    bce_s, bceE_s, sy_s, spy_s, P_s, s_cnt);
        process_elem(X[xs][1].y, T[ib][1].y, csB.x + csB.y + csB.z, bce_s, bceE_s, sy_s, spy_s, P_s, s_cnt);
        process_elem(X[xs][1].z, T[ib][1].z, csB.y + csB.z + csB.w, bce_s, bceE_s, sy_s, spy_s, P_s, s_cnt);
        process_elem(X[xs][1].w, T[ib][1].w, csB.z + csB.w + RB,    bce_s, bceE_s, sy_s, spy_s, P_s, s_cnt);

        // prefetch (compile-time pruned; distance = 3 steps)
        if (j < ROWS - 3) {
            const int rr = r0 + j + 4;                   // target row, may be 512 at last strip
            const int rc = rr > 511 ? 511 : rr;
            fT[ia] = (rr < 512) ? 1.f : 0.f;
            T[ia][0] = tg4[rc * 128 + cA];
            T[ia][1] = tg4[rc * 128 + cB];
            const int rx = r0 + j + 3;                   // logit row, always <= 511
            X[xs][0] = lg4[rx * 128 + cA];
            X[xs][1] = lg4[rx * 128 + cB];
        }
    }
    __syncthreads();

    // flush per-block histogram to its own global slice: plain coalesced stores
    // (kernel boundary publishes them to kernelBC).
    unsigned* g_c = ws->cnt + blockIdx.x * K_BINS;
    for (int i = tid; i < K_BINS; i += 256) g_c[i] = s_cnt[i];

    // block reduction of 5 accumulators
    for (int off = 32; off; off >>= 1) {
        bce_s  += __shfl_down(bce_s, off);
        bceE_s += __shfl_down(bceE_s, off);
        sy_s   += __shfl_down(sy_s, off);
        spy_s  += __shfl_down(spy_s, off);
        P_s    += __shfl_down(P_s, off);
    }
    if (lane == 0) {
        red[wave][0] = bce_s; red[wave][1] = bceE_s; red[wave][2] = sy_s;
        red[wave][3] = spy_s; red[wave][4] = P_s;
    }
    __syncthreads();
    if (tid == 0) {
        float a = 0.f, b = 0.f, c2 = 0.f, d = 0.f, e2 = 0.f;
        for (int w = 0; w < 4; ++w) {
            a += red[w][0]; b += red[w][1]; c2 += red[w][2];
            d += red[w][3]; e2 += red[w][4];
        }
        float* pf = ws->partf + blockIdx.x * 5;
        pf[0] = a; pf[1] = b; pf[2] = c2; pf[3] = d; pf[4] = e2;
        if (blockIdx.x == 0) ws->ticket = 0u;            // reset for kernelBC
    }
}

// Per-image Lovasz + dice ratio + bce partial reduce; the LAST block (sc1
// ticket protocol, no threadfence) folds the 32 per-image values into out[0].
__global__ __launch_bounds__(256) void kernelBC(Ws* __restrict__ ws,
                                                float* __restrict__ out) {
    __shared__ unsigned sc_a[256];
    __shared__ unsigned sc_p[256];
    __shared__ double   dred[4];
    __shared__ float    s_P, s_bce, s_bceE, s_dice;
    __shared__ int      s_last;

    const int img = blockIdx.x;
    const int tid = threadIdx.x;

    // ---- reduce the 32 per-block float partials of this image (wave 0) ----
    float pf0 = 0.f, pf1 = 0.f, pf2 = 0.f, pf3 = 0.f, pf4 = 0.f;
    if (tid < BPI) {
        const float* p = ws->partf + (img * BPI + tid) * 5;
        pf0 = p[0]; pf1 = p[1]; pf2 = p[2]; pf3 = p[3]; pf4 = p[4];
    }
    if (tid < 64) {
        for (int off = 16; off; off >>= 1) {
            pf0 += __shfl_down(pf0, off);
            pf1 += __shfl_down(pf1, off);
            pf2 += __shfl_down(pf2, off);
            pf3 += __shfl_down(pf3, off);
            pf4 += __shfl_down(pf4, off);
        }
        if (tid == 0) {
            s_bce  = pf0;
            s_bceE = pf1;
            s_dice = 2.f * pf2 / (pf3 + 1e-7f);
            s_P    = pf4;
        }
    }
    __syncthreads();

    // ---- gather 4 bins/thread (descending-bin order), summing 32 sub-hists ----
    const unsigned* __restrict__ cn = ws->cnt + img * BPI * K_BINS;
    unsigned la[4], lp[4];
    float    me[4];
    unsigned tot_a = 0, tot_p = 0;
#pragma unroll
    for (int j = 0; j < 4; ++j) {
        const int k = K_BINS - 1 - (tid * 4 + j);
        unsigned a = 0, p = 0;
#pragma unroll
        for (int b = 0; b < BPI; ++b) {
            const unsigned cpk = cn[b * K_BINS + k];
            a += cpk & 0xFFFFu;                          // per-slice unpack: 32-bit safe
            p += cpk >> 16;
        }
        la[j] = a; lp[j] = p;
        me[j] = ((float)k + 0.5f) * BIN_W;               // bin-midpoint error value
        tot_a += a; tot_p += p;
    }

    // block-wide inclusive scan of per-thread totals
    sc_a[tid] = tot_a; sc_p[tid] = tot_p;
    __syncthreads();
    for (int off = 1; off < 256; off <<= 1) {
        unsigned va = (tid >= off) ? sc_a[tid - off] : 0u;
        unsigned vp = (tid >= off) ? sc_p[tid - off] : 0u;
        __syncthreads();
        sc_a[tid] += va; sc_p[tid] += vp;
        __syncthreads();
    }
    const unsigned excl_a = sc_a[tid] - tot_a;
    const unsigned excl_p = sc_p[tid] - tot_p;

    const double P = (double)s_P;
    double run_a = (double)excl_a, run_p = (double)excl_p;
    double contrib = 0.0;
#pragma unroll
    for (int j = 0; j < 4; ++j) {
        const double m = (double)la[j];
        const double p = (double)lp[j];
        if (la[j]) {
            const double u = P + (run_a + 0.5 * m) - (run_p + 0.5 * p);
            const double c = run_p + 0.5 * p;
            contrib += (double)(lp[j] * me[j]) / u;                  // positives: dJ = 1/u
            const double den = u * (u - 1.0);
            if (den > 0.0)
                contrib += (double)((la[j] - lp[j]) * me[j]) * (P - c) / den;  // negatives
        }
        run_a += m; run_p += p;
    }

    for (int off = 32; off; off >>= 1) contrib += __shfl_down(contrib, off);
    const int wave = tid >> 6;
    const int lane = tid & 63;
    if (lane == 0) dred[wave] = contrib;
    __syncthreads();

    if (tid == 0) {
        const double tot = dred[0] + dred[1] + dred[2] + dred[3];
        // publish per-image result with agent-scope relaxed (sc1 write-through)
        // stores, drain, then relaxed ticket RMW — no wbl2/inv.
        float* vv = ws->vals + img * 4;
        __hip_atomic_store(&vv[0], s_bce,      __ATOMIC_RELAXED, AGENT);
        __hip_atomic_store(&vv[1], s_bceE,     __ATOMIC_RELAXED, AGENT);
        __hip_atomic_store(&vv[2], s_dice,     __ATOMIC_RELAXED, AGENT);
        __hip_atomic_store(&vv[3], (float)tot, __ATOMIC_RELAXED, AGENT);
        asm volatile("s_waitcnt vmcnt(0)" ::: "memory");
        const unsigned old = __hip_atomic_fetch_add(&ws->ticket, 1u,
                                                    __ATOMIC_RELAXED, AGENT);
        s_last = (old == NB - 1) ? 1 : 0;
    }
    __syncthreads();

    if (s_last) {
        if (tid < 64) {
            float vx = 0.f, vy = 0.f, vz = 0.f, vw = 0.f;
            if (tid < NB) {
                const float* vv = ws->vals + tid * 4;
                vx = __hip_atomic_load(&vv[0], __ATOMIC_RELAXED, AGENT);
                vy = __hip_atomic_load(&vv[1], __ATOMIC_RELAXED, AGENT);
                vz = __hip_atomic_load(&vv[2], __ATOMIC_RELAXED, AGENT);
                vw = __hip_atomic_load(&vv[3], __ATOMIC_RELAXED, AGENT);
            }
            for (int off = 16; off; off >>= 1) {
                vx += __shfl_down(vx, off);
                vy += __shfl_down(vy, off);
                vz += __shfl_down(vz, off);
                vw += __shfl_down(vw, off);
            }
            if (tid == 0) {
                const float invN = 1.f / (float)NTOT;
                const float bce      = vx * invN;
                const float boundary = (vx + 2.f * vy) * invN;
                const float dice     = 1.f - vz / (float)NB;
                const float lov      = vw / (float)NB;
                out[0] = 0.3f * bce + 0.3f * dice + 0.2f * boundary + 0.2f * lov;
            }
        }
    }
}

extern "C" void kernel_launch(void* const* d_in, const int* in_sizes, int n_in,
                              void* d_out, int out_size, void* d_ws, size_t ws_size,
                              hipStream_t stream) {
    const float* logits  = (const float*)d_in[0];
    const float* targets = (const float*)d_in[1];
    float* out = (float*)d_out;
    Ws* ws = (Ws*)d_ws;

    // no memset: hist/partials are per-block write-only slices; ticket is
    // zeroed by kernelA block 0 (stream-ordered before kernelBC).
    kernelA<<<NB * BPI, 256, 0, stream>>>(logits, targets, ws);
    kernelBC<<<NB, 256, 0, stream>>>(ws, out);
}

// Round 5
// 104.397 us; speedup vs baseline: 1.4313x; 1.0301x over previous
//
#include <hip/hip_runtime.h>
#include <hip/hip_bf16.h>

// HybridBCEDiceBoundaryLoss — scalar loss over logits/targets (32,1,512,512) fp32.
// loss = 0.3*BCE + 0.3*Dice + 0.2*BoundaryBCE + 0.2*LovaszHinge(per-image mean)
//
// Lovasz without sorting: counts-only histogram over e in (0,8), 1024 bins,
// suffix-scan ranks, bin-midpoint values (2nd-order accurate).
//
// R13: kernelBC latency polish (kernelA frozen at R12's 107.5us config).
//  - gather: per-thread bins are contiguous & 16B-aligned -> uint4 loads
//    (128 scalar dword loads -> 32 dwordx4 per thread).
//  - scan: wave-level __shfl_up inclusive scan + cross-wave offsets
//    (16 __syncthreads -> 1).
// Structure: 2 nodes, no memset; ticket zeroed by kernelA block 0; final fold
// uses the R11-validated sc1 protocol (agent-scope relaxed + vmcnt drain).

#define NB      32
#define HH      512
#define WW      512
#define HW      (HH*WW)          // 262144
#define NTOT    (NB*HW)          // 8388608
#define K_BINS  1024
#define INV_H   128.0f           // K_BINS / 8.0 range
#define BIN_W   (1.0f/128.0f)
#define ROWS    4                // rows per wave
#define BPI     32               // kernelA blocks per image

#define AGENT   __HIP_MEMORY_SCOPE_AGENT

struct Ws {
    unsigned ticket;             // zeroed by kernelA block 0 (stream-ordered)
    unsigned cnt[NB*BPI*K_BINS]; // per-block packed hist: low16=all, high16=pos (4 MB)
    float    partf[NB*BPI*5];    // per-block {bce, bceE, sy, spy, P}
    float    vals[NB*4];         // per-image {bce, bceE, dice_ratio, lov}
};

__device__ __forceinline__ void process_elem(float x, float y, float wsum,
                                             float& bce_s, float& bceE_s, float& sy_s,
                                             float& spy_s, float& P_s,
                                             unsigned* s_cnt) {
    const float ax = fabsf(x);
    const float t  = __expf(-ax);                       // exp(-|x|)
    const float bce = fmaxf(x, 0.f) - x * y + __logf(1.f + t);
    const float inv = __builtin_amdgcn_rcpf(1.f + t);
    const float s = (x >= 0.f) ? inv : t * inv;         // sigmoid(x)
    const bool edge = (wsum > 0.5f) && (wsum < 8.5f);   // 1..8 of 9 ones

    bce_s  += bce;
    bceE_s += edge ? bce : 0.f;
    sy_s   += s * y;
    spy_s  += s + y;
    P_s    += y;

    const float e = 1.f - x * (2.f * y - 1.f);
    if (e > 0.f) {
        int b = (int)(e * INV_H);
        if (b > K_BINS - 1) b = K_BINS - 1;
        atomicAdd(&s_cnt[b], (y > 0.5f) ? 0x10001u : 1u);
    }
}

__global__ __launch_bounds__(256, 4) void kernelA(const float* __restrict__ logits,
                                                  const float* __restrict__ targets,
                                                  Ws* __restrict__ ws) {
    __shared__ unsigned s_cnt[K_BINS];
    __shared__ float    red[4][5];

    const int tid  = threadIdx.x;
    const int lane = tid & 63;
    const int wave = tid >> 6;
    for (int i = tid; i < K_BINS; i += 256) s_cnt[i] = 0u;
    __syncthreads();

    const int img   = blockIdx.x >> 5;                   // 32 blocks per image
    const int strip = ((blockIdx.x & 31) << 2) | wave;   // 0..127
    const int r0    = strip * ROWS;                      // this wave: rows r0..r0+3

    const float4* __restrict__ tg4 = (const float4*)(targets + img * HW);
    const float4* __restrict__ lg4 = (const float4*)(logits  + img * HW);
    const int cA = lane;         // f4 cols 4*lane   .. 4*lane+3
    const int cB = 64 + lane;    // f4 cols 256+4*lane ..

    // circular windows: T rows r-1..r+1 live in slots (j)%5,(j+1)%5,(j+2)%5
    float4 T[5][2]; float fT[5];
    float4 X[3][2];

#pragma unroll
    for (int s = 0; s < 5; ++s) {                        // rows r0-1 .. r0+3
        const int rr = r0 - 1 + s;
        const int rc = rr < 0 ? 0 : (rr > 511 ? 511 : rr);
        fT[s] = (rr >= 0 && rr < 512) ? 1.f : 0.f;
        T[s][0] = tg4[rc * 128 + cA];
        T[s][1] = tg4[rc * 128 + cB];
    }
#pragma unroll
    for (int s = 0; s < 3; ++s) {                        // logit rows r0 .. r0+2
        const int rr = r0 + s;
        X[s][0] = lg4[rr * 128 + cA];
        X[s][1] = lg4[rr * 128 + cB];
    }

    float bce_s = 0.f, bceE_s = 0.f, sy_s = 0.f, spy_s = 0.f, P_s = 0.f;

#pragma unroll
    for (int j = 0; j < ROWS; ++j) {
        const int ia = j % 5, ib = (j + 1) % 5, ic = (j + 2) % 5;
        const int xs = j % 3;
        const float fa = fT[ia], fc = fT[ic];

        // column triple-sums for cols 4*lane.. (chunk A) and 256+4*lane.. (chunk B)
        float4 csA, csB;
        csA.x = fmaf(T[ia][0].x, fa, fmaf(T[ic][0].x, fc, T[ib][0].x));
        csA.y = fmaf(T[ia][0].y, fa, fmaf(T[ic][0].y, fc, T[ib][0].y));
        csA.z = fmaf(T[ia][0].z, fa, fmaf(T[ic][0].z, fc, T[ib][0].z));
        csA.w = fmaf(T[ia][0].w, fa, fmaf(T[ic][0].w, fc, T[ib][0].w));
        csB.x = fmaf(T[ia][1].x, fa, fmaf(T[ic][1].x, fc, T[ib][1].x));
        csB.y = fmaf(T[ia][1].y, fa, fmaf(T[ic][1].y, fc, T[ib][1].y));
        csB.z = fmaf(T[ia][1].z, fa, fmaf(T[ic][1].z, fc, T[ib][1].z));
        csB.w = fmaf(T[ia][1].w, fa, fmaf(T[ic][1].w, fc, T[ib][1].w));

        // neighbor columns via shuffles (wave owns the full 512-col row)
        const float upA  = __shfl_up(csA.w, 1);
        const float dnA  = __shfl_down(csA.x, 1);
        const float upB  = __shfl_up(csB.w, 1);
        const float dnB  = __shfl_down(csB.x, 1);
        const float bc0  = __shfl(csB.x, 0);    // col 256 triple-sum
        const float bc63 = __shfl(csA.w, 63);   // col 255 triple-sum
        const float LA = (lane == 0)  ? 0.f  : upA;
        const float RA = (lane == 63) ? bc0  : dnA;
        const float LB = (lane == 0)  ? bc63 : upB;
        const float RB = (lane == 63) ? 0.f  : dnB;

        process_elem(X[xs][0].x, T[ib][0].x, LA + csA.x + csA.y,    bce_s, bceE_s, sy_s, spy_s, P_s, s_cnt);
        process_elem(X[xs][0].y, T[ib][0].y, csA.x + csA.y + csA.z, bce_s, bceE_s, sy_s, spy_s, P_s, s_cnt);
        process_elem(X[xs][0].z, T[ib][0].z, csA.y + csA.z + csA.w, bce_s, bceE_s, sy_s, spy_s, P_s, s_cnt);
        process_elem(X[xs][0].w, T[ib][0].w, csA.z + csA.w + RA,    bce_s, bceE_s, sy_s, spy_s, P_s, s_cnt);
        process_elem(X[xs][1].x, T[ib][1].x, LB + csB.x + csB.y,    bce_s, bceE_s, sy_s, spy_s, P_s, s_cnt);
        process_elem(X[xs][1].y, T[ib][1].y, csB.x + csB.y + csB.z, bce_s, bceE_s, sy_s, spy_s, P_s, s_cnt);
        process_elem(X[xs][1].z, T[ib][1].z, csB.y + csB.z + csB.w, bce_s, bceE_s, sy_s, spy_s, P_s, s_cnt);
        process_elem(X[xs][1].w, T[ib][1].w, csB.z + csB.w + RB,    bce_s, bceE_s, sy_s, spy_s, P_s, s_cnt);

        // prefetch (compile-time pruned; distance = 3 steps)
        if (j < ROWS - 3) {
            const int rr = r0 + j + 4;                   // target row, may be 512 at last strip
            const int rc = rr > 511 ? 511 : rr;
            fT[ia] = (rr < 512) ? 1.f : 0.f;
            T[ia][0] = tg4[rc * 128 + cA];
            T[ia][1] = tg4[rc * 128 + cB];
            const int rx = r0 + j + 3;                   // logit row, always <= 511
            X[xs][0] = lg4[rx * 128 + cA];
            X[xs][1] = lg4[rx * 128 + cB];
        }
    }
    __syncthreads();

    // flush per-block histogram to its own global slice: plain coalesced stores
    // (kernel boundary publishes them to kernelBC).
    unsigned* g_c = ws->cnt + blockIdx.x * K_BINS;
    for (int i = tid; i < K_BINS; i += 256) g_c[i] = s_cnt[i];

    // block reduction of 5 accumulators
    for (int off = 32; off; off >>= 1) {
        bce_s  += __shfl_down(bce_s, off);
        bceE_s += __shfl_down(bceE_s, off);
        sy_s   += __shfl_down(sy_s, off);
        spy_s  += __shfl_down(spy_s, off);
        P_s    += __shfl_down(P_s, off);
    }
    if (lane == 0) {
        red[wave][0] = bce_s; red[wave][1] = bceE_s; red[wave][2] = sy_s;
        red[wave][3] = spy_s; red[wave][4] = P_s;
    }
    __syncthreads();
    if (tid == 0) {
        float a = 0.f, b = 0.f, c2 = 0.f, d = 0.f, e2 = 0.f;
        for (int w = 0; w < 4; ++w) {
            a += red[w][0]; b += red[w][1]; c2 += red[w][2];
            d += red[w][3]; e2 += red[w][4];
        }
        float* pf = ws->partf + blockIdx.x * 5;
        pf[0] = a; pf[1] = b; pf[2] = c2; pf[3] = d; pf[4] = e2;
        if (blockIdx.x == 0) ws->ticket = 0u;            // reset for kernelBC
    }
}

// Per-image Lovasz + dice ratio + bce partial reduce; the LAST block (sc1
// ticket protocol, no threadfence) folds the 32 per-image values into out[0].
__global__ __launch_bounds__(256) void kernelBC(Ws* __restrict__ ws,
                                                float* __restrict__ out) {
    __shared__ unsigned wtot_a[4], wtot_p[4];
    __shared__ double   dred[4];
    __shared__ float    s_P, s_bce, s_bceE, s_dice;
    __shared__ int      s_last;

    const int img  = blockIdx.x;
    const int tid  = threadIdx.x;
    const int lane = tid & 63;
    const int wave = tid >> 6;

    // ---- reduce the 32 per-block float partials of this image (wave 0) ----
    float pf0 = 0.f, pf1 = 0.f, pf2 = 0.f, pf3 = 0.f, pf4 = 0.f;
    if (tid < BPI) {
        const float* p = ws->partf + (img * BPI + tid) * 5;
        pf0 = p[0]; pf1 = p[1]; pf2 = p[2]; pf3 = p[3]; pf4 = p[4];
    }
    if (tid < 64) {
        for (int off = 16; off; off >>= 1) {
            pf0 += __shfl_down(pf0, off);
            pf1 += __shfl_down(pf1, off);
            pf2 += __shfl_down(pf2, off);
            pf3 += __shfl_down(pf3, off);
            pf4 += __shfl_down(pf4, off);
        }
        if (tid == 0) {
            s_bce  = pf0;
            s_bceE = pf1;
            s_dice = 2.f * pf2 / (pf3 + 1e-7f);
            s_P    = pf4;
        }
    }

    // ---- gather: thread owns 4 CONTIGUOUS bins (16B-aligned) -> uint4 loads ----
    // thread tid covers bins [k0 .. k0+3], k0 = 1020 - 4*tid; thread order is
    // descending-bin, and within the thread j=0..3 maps to k0+3..k0 (descending).
    const unsigned* __restrict__ cn = ws->cnt + img * BPI * K_BINS;
    const int k0 = K_BINS - 4 - (tid * 4);
    unsigned a4x = 0, a4y = 0, a4z = 0, a4w = 0;
    unsigned p4x = 0, p4y = 0, p4z = 0, p4w = 0;
#pragma unroll
    for (int b = 0; b < BPI; ++b) {
        const uint4 cpk = *reinterpret_cast<const uint4*>(cn + b * K_BINS + k0);
        a4x += cpk.x & 0xFFFFu;  p4x += cpk.x >> 16;
        a4y += cpk.y & 0xFFFFu;  p4y += cpk.y >> 16;
        a4z += cpk.z & 0xFFFFu;  p4z += cpk.z >> 16;
        a4w += cpk.w & 0xFFFFu;  p4w += cpk.w >> 16;
    }
    unsigned la[4], lp[4];
    float    me[4];
    la[0] = a4w; la[1] = a4z; la[2] = a4y; la[3] = a4x;   // descending bins
    lp[0] = p4w; lp[1] = p4z; lp[2] = p4y; lp[3] = p4x;
#pragma unroll
    for (int j = 0; j < 4; ++j)
        me[j] = ((float)(k0 + 3 - j) + 0.5f) * BIN_W;     // bin-midpoint error value
    const unsigned tot_a = la[0] + la[1] + la[2] + la[3];
    const unsigned tot_p = lp[0] + lp[1] + lp[2] + lp[3];

    // ---- scan: wave-level shuffle inclusive scan + cross-wave offsets ----
    unsigned inc_a = tot_a, inc_p = tot_p;
#pragma unroll
    for (int off = 1; off < 64; off <<= 1) {
        const unsigned va = __shfl_up(inc_a, off);
        const unsigned vp = __shfl_up(inc_p, off);
        if (lane >= off) { inc_a += va; inc_p += vp; }
    }
    if (lane == 63) { wtot_a[wave] = inc_a; wtot_p[wave] = inc_p; }
    __syncthreads();
    unsigned offa = 0, offp = 0;
#pragma unroll
    for (int w = 0; w < 3; ++w) {
        if (w < wave) { offa += wtot_a[w]; offp += wtot_p[w]; }
    }
    const unsigned excl_a = offa + inc_a - tot_a;
    const unsigned excl_p = offp + inc_p - tot_p;

    const double P = (double)s_P;                         // s_P valid: barrier above
    double run_a = (double)excl_a, run_p = (double)excl_p;
    double contrib = 0.0;
#pragma unroll
    for (int j = 0; j < 4; ++j) {
        const double m = (double)la[j];
        const double p = (double)lp[j];
        if (la[j]) {
            const double u = P + (run_a + 0.5 * m) - (run_p + 0.5 * p);
            const double c = run_p + 0.5 * p;
            contrib += (double)(lp[j] * me[j]) / u;                  // positives: dJ = 1/u
            const double den = u * (u - 1.0);
            if (den > 0.0)
                contrib += (double)((la[j] - lp[j]) * me[j]) * (P - c) / den;  // negatives
        }
        run_a += m; run_p += p;
    }

    for (int off = 32; off; off >>= 1) contrib += __shfl_down(contrib, off);
    if (lane == 0) dred[wave] = contrib;
    __syncthreads();

    if (tid == 0) {
        const double tot = dred[0] + dred[1] + dred[2] + dred[3];
        // publish per-image result with agent-scope relaxed (sc1 write-through)
        // stores, drain, then relaxed ticket RMW — no wbl2/inv.
        float* vv = ws->vals + img * 4;
        __hip_atomic_store(&vv[0], s_bce,      __ATOMIC_RELAXED, AGENT);
        __hip_atomic_store(&vv[1], s_bceE,     __ATOMIC_RELAXED, AGENT);
        __hip_atomic_store(&vv[2], s_dice,     __ATOMIC_RELAXED, AGENT);
        __hip_atomic_store(&vv[3], (float)tot, __ATOMIC_RELAXED, AGENT);
        asm volatile("s_waitcnt vmcnt(0)" ::: "memory");
        const unsigned old = __hip_atomic_fetch_add(&ws->ticket, 1u,
                                                    __ATOMIC_RELAXED, AGENT);
        s_last = (old == NB - 1) ? 1 : 0;
    }
    __syncthreads();

    if (s_last) {
        if (tid < 64) {
            float vx = 0.f, vy = 0.f, vz = 0.f, vw = 0.f;
            if (tid < NB) {
                const float* vv = ws->vals + tid * 4;
                vx = __hip_atomic_load(&vv[0], __ATOMIC_RELAXED, AGENT);
                vy = __hip_atomic_load(&vv[1], __ATOMIC_RELAXED, AGENT);
                vz = __hip_atomic_load(&vv[2], __ATOMIC_RELAXED, AGENT);
                vw = __hip_atomic_load(&vv[3], __ATOMIC_RELAXED, AGENT);
            }
            for (int off = 16; off; off >>= 1) {
                vx += __shfl_down(vx, off);
                vy += __shfl_down(vy, off);
                vz += __shfl_down(vz, off);
                vw += __shfl_down(vw, off);
            }
            if (tid == 0) {
                const float invN = 1.f / (float)NTOT;
                const float bce      = vx * invN;
                const float boundary = (vx + 2.f * vy) * invN;
                const float dice     = 1.f - vz / (float)NB;
                const float lov      = vw / (float)NB;
                out[0] = 0.3f * bce + 0.3f * dice + 0.2f * boundary + 0.2f * lov;
            }
        }
    }
}

extern "C" void kernel_launch(void* const* d_in, const int* in_sizes, int n_in,
                              void* d_out, int out_size, void* d_ws, size_t ws_size,
                              hipStream_t stream) {
    const float* logits  = (const float*)d_in[0];
    const float* targets = (const float*)d_in[1];
    float* out = (float*)d_out;
    Ws* ws = (Ws*)d_ws;

    // no memset: hist/partials are per-block write-only slices; ticket is
    // zeroed by kernelA block 0 (stream-ordered before kernelBC).
    kernelA<<<NB * BPI, 256, 0, stream>>>(logits, targets, ws);
    kernelBC<<<NB, 256, 0, stream>>>(ws, out);
}